// Round 2
// baseline (125.389 us; speedup 1.0000x reference)
//
#include <hip/hip_runtime.h>
#include <hip/hip_cooperative_groups.h>

namespace cg = cooperative_groups;

// RefinementCAM: B=4, C=256, H=W=64, N=4096.
// Factorized: out[b,n] = s[b,n] * (feat[b,:,n] . v[b,:]),
//   v[b,c] = sum_m feat[b,c,m] * w[b,m],  w = s*cam,  s = m/max(||feat*m||,1e-12).
// Single cooperative kernel, 256 blocks x 256 threads, 4 grid syncs.

constexpr int B  = 4;
constexpr int C  = 256;
constexpr int N  = 4096;
constexpr int BN = B * N;       // 16384

__device__ __forceinline__ float wsum(float v) {
#pragma unroll
    for (int o = 32; o > 0; o >>= 1) v += __shfl_down(v, o, 64);
    return v;
}
__device__ __forceinline__ float wmin(float v) {
#pragma unroll
    for (int o = 32; o > 0; o >>= 1) v = fminf(v, __shfl_down(v, o, 64));
    return v;
}
__device__ __forceinline__ float wmax(float v) {
#pragma unroll
    for (int o = 32; o > 0; o >>= 1) v = fmaxf(v, __shfl_down(v, o, 64));
    return v;
}

__global__ void __launch_bounds__(256) fused_kernel(
    const float* __restrict__ cam, const float* __restrict__ feat,
    float* __restrict__ out, float* __restrict__ ws)
{
    cg::grid_group grid = cg::this_grid();

    float* s    = ws;            // 16384
    float* w    = ws + 16384;    // 16384
    float* v    = ws + 32768;    // 1024
    float* ob   = ws + 33792;    // 16384
    float* bmn  = ws + 50176;    // 256
    float* bmx  = ws + 50432;    // 256
    float* part = ws + 50688;    // 256

    const int blk  = blockIdx.x;   // 0..255
    const int tx   = threadIdx.x;  // 0..255
    const int lane = tx & 63;
    const int wid  = tx >> 6;      // 0..3: channel group in phases A/C

    __shared__ float red[4][64];
    __shared__ float vs[C];
    __shared__ float sb[8];

    const int p = blk * 64 + lane;   // pixel owned by (lane) in phases A/C/E
    const int b = blk >> 6;          // batch, uniform per block (64 blocks/batch)
    const int n = p & (N - 1);

    // ---- A: per-pixel channel norm -> s, w (channel dim split over 4 waves) ----
    {
        const float* fp = feat + (size_t)b * (C * N) + (size_t)(wid * 64) * N + n;
        float ss = 0.f;
#pragma unroll 8
        for (int cc = 0; cc < 64; ++cc) {
            float x = fp[(size_t)cc * N];   // lanes contiguous in n -> coalesced
            ss = fmaf(x, x, ss);
        }
        red[wid][lane] = ss;
        __syncthreads();
        if (wid == 0) {
            float cv = cam[p];
            float m  = ((cv >= 0.3f ? 1.f : 0.f) + (cv >= 0.4f ? 1.f : 0.f) +
                        (cv >= 0.5f ? 1.f : 0.f)) * (1.f / 3.f);
            float tot = (red[0][lane] + red[1][lane]) + (red[2][lane] + red[3][lane]);
            tot *= m * m;                              // ||feat*m||^2 = m^2*||feat||^2
            float sc = m / fmaxf(sqrtf(tot), 1e-12f);
            s[p] = sc;
            w[p] = sc * cv;
        }
    }
    grid.sync();

    // ---- B: v[b,c] = feat[b,c,:] . w[b,:]   (4 rows/block, 1 row/wave) ----
    {
        int bc = blk * 4 + wid;                 // 0..1023
        int bb = bc >> 8, c = bc & (C - 1);
        const float* fp = feat + (size_t)bb * (C * N) + (size_t)c * N;
        const float* wp = w + bb * N;
        float acc = 0.f;
#pragma unroll
        for (int i = 0; i < 16; ++i) {
            int idx = (i * 64 + lane) * 4;
            float4 x = *(const float4*)(fp + idx);
            float4 y = *(const float4*)(wp + idx);
            acc = fmaf(x.x, y.x, acc); acc = fmaf(x.y, y.y, acc);
            acc = fmaf(x.z, y.z, acc); acc = fmaf(x.w, y.w, acc);
        }
        acc = wsum(acc);
        if (lane == 0) v[bc] = acc;
    }
    grid.sync();

    // ---- C: ob[p] = s[p] * (feat[b,:,n] . v[b,:]); per-block min/max ----
    {
        vs[tx] = v[b * C + tx];
        __syncthreads();
        const float* fp = feat + (size_t)b * (C * N) + n;
        float acc = 0.f;
#pragma unroll 8
        for (int cc = 0; cc < 64; ++cc) {
            int c = wid * 64 + cc;
            acc = fmaf(fp[(size_t)c * N], vs[c], acc);  // vs broadcast: conflict-free
        }
        red[wid][lane] = acc;
        __syncthreads();
        if (wid == 0) {
            float o = s[p] * ((red[0][lane] + red[1][lane]) + (red[2][lane] + red[3][lane]));
            ob[p] = o;
            float mn = wmin(o), mx = wmax(o);
            if (lane == 0) { bmn[blk] = mn; bmx[blk] = mx; }
        }
    }
    grid.sync();

    // ---- D+E: batch min/max (redundant per block), rescale, |ref-cam| partials ----
    {
        if (wid == 0) {
            float x = wmin(bmn[b * 64 + lane]);
            if (lane == 0) sb[0] = x;
        } else if (wid == 1) {
            float x = wmax(bmx[b * 64 + lane]);
            if (lane == 0) sb[1] = x;
        }
        __syncthreads();
        if (wid == 0) {
            float mn  = sb[0];
            float mxa = sb[1] + 1e-5f;
            float r = (ob[p] - mn) / (mxa - mn);
            out[p] = r;
            float ad = wsum(fabsf(r - cam[p]));
            if (lane == 0) part[blk] = ad;
        }
    }
    grid.sync();

    // ---- F: loss = mean |ref - cam| ----
    if (blk == 0) {
        float x = wsum(part[tx]);
        if (lane == 0) sb[wid] = x;
        __syncthreads();
        if (tx == 0) out[BN] = (sb[0] + sb[1] + sb[2] + sb[3]) * (1.f / (float)BN);
    }
}

extern "C" void kernel_launch(void* const* d_in, const int* in_sizes, int n_in,
                              void* d_out, int out_size, void* d_ws, size_t ws_size,
                              hipStream_t stream) {
    const float* cam  = (const float*)d_in[0];   // (4,64,64)
    const float* feat = (const float*)d_in[1];   // (4,256,64,64)
    float* out = (float*)d_out;                  // [16384 ref][1 loss]
    float* ws  = (float*)d_ws;

    void* args[] = { (void*)&cam, (void*)&feat, (void*)&out, (void*)&ws };
    hipLaunchCooperativeKernel((void*)fused_kernel, dim3(256), dim3(256),
                               args, 0, stream);
}

// Round 3
// 20.367 us; speedup vs baseline: 6.1565x; 6.1565x over previous
//
#include <hip/hip_runtime.h>

// RefinementCAM: B=4, C=256, H=W=64, N=4096.
// Factorized: out[b,n] = s[b,n] * (feat[b,:,n] . v[b,:]),
//   v[b,c] = sum_m feat[b,c,m] * w[b,m],  w = s*cam,  s = m/max(m*||feat[:,n]||,1e-12).
// 4 kernels, all high-occupancy; loss finished via last-block atomic pattern.

constexpr int B  = 4;
constexpr int C  = 256;
constexpr int N  = 4096;
constexpr int BN = B * N;       // 16384
constexpr int CN = C * N;

__device__ __forceinline__ float wsum(float v) {
#pragma unroll
    for (int o = 32; o > 0; o >>= 1) v += __shfl_down(v, o, 64);
    return v;
}
__device__ __forceinline__ float wmin64(float v) {
#pragma unroll
    for (int o = 32; o > 0; o >>= 1) v = fminf(v, __shfl_down(v, o, 64));
    return v;
}
__device__ __forceinline__ float wmax64(float v) {
#pragma unroll
    for (int o = 32; o > 0; o >>= 1) v = fmaxf(v, __shfl_down(v, o, 64));
    return v;
}

// K1: 512 blocks x 256 thr. Block owns 32 pixels; 8 channel-groups of 32.
// s = m/denom, w = s*cam. Also re-zeros the loss counter each call.
__global__ void __launch_bounds__(256) k_norm(
    const float* __restrict__ cam, const float* __restrict__ feat,
    float* __restrict__ s, float* __restrict__ w, unsigned int* __restrict__ cnt)
{
    if (blockIdx.x == 0 && threadIdx.x == 0) *cnt = 0u;
    const int t   = threadIdx.x;
    const int pix = t & 31;          // pixel within block
    const int g   = t >> 5;          // channel group 0..7
    const int p   = blockIdx.x * 32 + pix;
    const int b   = p >> 12;         // uniform per block
    const int n   = p & (N - 1);

    const float* fp = feat + (size_t)b * CN + (size_t)(g * 32) * N + n;
    float ss = 0.f;
#pragma unroll 8
    for (int cc = 0; cc < 32; ++cc) {
        float x = fp[(size_t)cc * N];       // 32 consecutive lanes -> coalesced
        ss = fmaf(x, x, ss);
    }
    __shared__ float red[8][33];
    red[g][pix] = ss;
    __syncthreads();
    if (t < 32) {
        float tot = 0.f;
#pragma unroll
        for (int gg = 0; gg < 8; ++gg) tot += red[gg][t];
        float cv = cam[blockIdx.x * 32 + t];
        float m  = ((cv >= 0.3f ? 1.f : 0.f) + (cv >= 0.4f ? 1.f : 0.f) +
                    (cv >= 0.5f ? 1.f : 0.f)) * (1.f / 3.f);
        tot *= m * m;                        // ||feat*m||^2 = m^2 * ||feat||^2
        float sc = m / fmaxf(sqrtf(tot), 1e-12f);
        int q = blockIdx.x * 32 + t;
        s[q] = sc;
        w[q] = sc * cv;
    }
}

// K2: 1024 blocks x 256 thr. v[b,c] = feat[b,c,:] . w[b,:].
__global__ void __launch_bounds__(256) k_v(
    const float* __restrict__ feat, const float* __restrict__ w,
    float* __restrict__ v)
{
    const int bc = blockIdx.x;               // 0..1023
    const int b = bc >> 8, c = bc & (C - 1);
    const float* fp = feat + (size_t)b * CN + (size_t)c * N;
    const float* wp = w + b * N;
    const int t = threadIdx.x;
    float acc = 0.f;
#pragma unroll
    for (int i = 0; i < 4; ++i) {
        int idx = (i * 256 + t) * 4;
        float4 x = *(const float4*)(fp + idx);
        float4 y = *(const float4*)(wp + idx);
        acc = fmaf(x.x, y.x, acc); acc = fmaf(x.y, y.y, acc);
        acc = fmaf(x.z, y.z, acc); acc = fmaf(x.w, y.w, acc);
    }
    __shared__ float red[4];
    float tot = wsum(acc);
    if ((t & 63) == 0) red[t >> 6] = tot;
    __syncthreads();
    if (t == 0) v[bc] = (red[0] + red[1]) + (red[2] + red[3]);
}

// K3: 512 blocks x 256 thr, same shape as K1. ob = s * (feat[:,n].v); block min/max.
__global__ void __launch_bounds__(256) k_out(
    const float* __restrict__ feat, const float* __restrict__ s,
    const float* __restrict__ v, float* __restrict__ ob,
    float* __restrict__ bmn, float* __restrict__ bmx)
{
    const int t   = threadIdx.x;
    const int pix = t & 31;
    const int g   = t >> 5;
    const int p   = blockIdx.x * 32 + pix;
    const int b   = p >> 12;
    const int n   = p & (N - 1);

    __shared__ float vs[C];
    vs[t] = v[b * C + t];
    __syncthreads();

    const float* fp = feat + (size_t)b * CN + (size_t)(g * 32) * N + n;
    float acc = 0.f;
#pragma unroll 8
    for (int cc = 0; cc < 32; ++cc)
        acc = fmaf(fp[(size_t)cc * N], vs[g * 32 + cc], acc);  // vs broadcast

    __shared__ float red[8][33];
    red[g][pix] = acc;
    __syncthreads();
    if (t < 32) {
        float tot = 0.f;
#pragma unroll
        for (int gg = 0; gg < 8; ++gg) tot += red[gg][t];
        float o = s[blockIdx.x * 32 + t] * tot;
        ob[blockIdx.x * 32 + t] = o;
        // min/max over the 32 values (lanes 0..31 of wave 0)
        float mn = o, mx = o;
#pragma unroll
        for (int o2 = 16; o2 > 0; o2 >>= 1) {
            mn = fminf(mn, __shfl_down(mn, o2, 64));
            mx = fmaxf(mx, __shfl_down(mx, o2, 64));
        }
        if (t == 0) { bmn[blockIdx.x] = mn; bmx[blockIdx.x] = mx; }
    }
}

// K4: 64 blocks x 256 thr. Batch minmax (from 128 block-entries), rescale,
// |ref-cam| partial; last block finishes the loss (fixed-order sum).
__global__ void __launch_bounds__(256) k_final(
    const float* __restrict__ ob, const float* __restrict__ cam,
    const float* __restrict__ bmn, const float* __restrict__ bmx,
    float* __restrict__ out, float* __restrict__ part, unsigned int* __restrict__ cnt)
{
    const int t = threadIdx.x, blk = blockIdx.x;
    const int p = blk * 256 + t;
    const int b = blk >> 4;                 // 16 blocks per batch

    __shared__ float sh[2];
    if (t < 64) {
        float a = fminf(bmn[b * 128 + t], bmn[b * 128 + 64 + t]);
        a = wmin64(a);
        if (t == 0) sh[0] = a;
    } else if (t < 128) {
        int l = t - 64;
        float a = fmaxf(bmx[b * 128 + l], bmx[b * 128 + 64 + l]);
        a = wmax64(a);
        if (l == 0) sh[1] = a;
    }
    __syncthreads();
    const float mn = sh[0];
    const float mx = sh[1] + 1e-5f;

    float r = (ob[p] - mn) / (mx - mn);
    out[p] = r;
    float ad = fabsf(r - cam[p]);

    __shared__ float red[4];
    float ps = wsum(ad);
    if ((t & 63) == 0) red[t >> 6] = ps;
    __syncthreads();

    __shared__ int lastflag;
    if (t == 0) {
        float tot = (red[0] + red[1]) + (red[2] + red[3]);
        __hip_atomic_store(&part[blk], tot, __ATOMIC_RELEASE, __HIP_MEMORY_SCOPE_AGENT);
        unsigned old = __hip_atomic_fetch_add(cnt, 1u, __ATOMIC_ACQ_REL,
                                              __HIP_MEMORY_SCOPE_AGENT);
        lastflag = (old == 63u) ? 1 : 0;
    }
    __syncthreads();
    if (lastflag && t < 64) {
        float x = __hip_atomic_load(&part[t], __ATOMIC_ACQUIRE,
                                    __HIP_MEMORY_SCOPE_AGENT);
        x = wsum(x);                        // fixed-order: deterministic
        if (t == 0) out[BN] = x * (1.f / (float)BN);
    }
}

extern "C" void kernel_launch(void* const* d_in, const int* in_sizes, int n_in,
                              void* d_out, int out_size, void* d_ws, size_t ws_size,
                              hipStream_t stream) {
    const float* cam  = (const float*)d_in[0];   // (4,64,64)
    const float* feat = (const float*)d_in[1];   // (4,256,64,64)
    float* out = (float*)d_out;                  // [16384 ref][1 loss]
    float* ws  = (float*)d_ws;

    float* s    = ws;                 // 16384
    float* w    = ws + 16384;         // 16384
    float* v    = ws + 32768;         // 1024
    float* ob   = ws + 33792;         // 16384
    float* bmn  = ws + 50176;         // 512
    float* bmx  = ws + 50688;         // 512
    float* part = ws + 51200;         // 64
    unsigned int* cnt = (unsigned int*)(ws + 51264);

    k_norm <<<512,  256, 0, stream>>>(cam, feat, s, w, cnt);
    k_v    <<<1024, 256, 0, stream>>>(feat, w, v);
    k_out  <<<512,  256, 0, stream>>>(feat, s, v, ob, bmn, bmx);
    k_final<<<64,   256, 0, stream>>>(ob, cam, bmn, bmx, out, part, cnt);
}